// Round 5
// baseline (445.737 us; speedup 1.0000x reference)
//
#include <hip/hip_runtime.h>

// GCN 3-layer, fused aggregate+transform per layer:
//   deg/norms -> CSR by dst ->
//   L1 fused: agg from emb-in-LDS via (label,out_norm); h1s=relu(agg@W1+b1)*out_norm
//   L2 fused: agg from h1s rows (global);               h2s=relu(agg@W2+b2)*out_norm
//   L3: t=h2s@W3 (tiled, row stride 52, cols 50/51 zeroed); out=in_norm*gather4(t)+b3
#define N_NODES 50000
#define N_EDGES 800000
#define EMB     64
#define HID     96
#define NLAB    50
#define NB_SCAN ((N_NODES + 255) / 256)   // 196
#define TSTRIDE 52                        // padded row stride of t (float4-able)

__global__ void deg_kernel(const int* __restrict__ src, const int* __restrict__ dst,
                           int* __restrict__ deg_out, int* __restrict__ deg_in) {
    int i = blockIdx.x * blockDim.x + threadIdx.x;
    if (i < N_EDGES) {
        atomicAdd(&deg_out[src[i]], 1);
        atomicAdd(&deg_in[dst[i]], 1);
    }
}

// norms + packed per-node (label, out_norm) for the fused layer-1 gather
__global__ void norm_kernel(const int* __restrict__ deg_out, const int* __restrict__ deg_in,
                            const int* __restrict__ labels,
                            float* __restrict__ out_norm, float* __restrict__ in_norm,
                            int2* __restrict__ node_info) {
    int i = blockIdx.x * blockDim.x + threadIdx.x;
    if (i < N_NODES) {
        float on = rsqrtf(fmaxf((float)deg_out[i], 1.0f));
        out_norm[i] = on;
        in_norm[i]  = rsqrtf(fmaxf((float)deg_in[i], 1.0f));
        node_info[i] = make_int2(labels[i], __float_as_int(on));
    }
}

// --- exclusive scan of deg_in -> row_off (and wr cursor copy) ---
__global__ void scan1_kernel(const int* __restrict__ deg, int* __restrict__ bsum) {
    __shared__ int s[256];
    int t = threadIdx.x, i = blockIdx.x * 256 + t;
    s[t] = (i < N_NODES) ? deg[i] : 0;
    for (int off = 128; off > 0; off >>= 1) {
        __syncthreads();
        if (t < off) s[t] += s[t + off];
    }
    if (t == 0) bsum[blockIdx.x] = s[0];
}

__global__ void scan2_kernel(const int* __restrict__ bsum, int* __restrict__ bscan) {
    __shared__ int s[256];
    int t = threadIdx.x;
    int own = (t < NB_SCAN) ? bsum[t] : 0;
    s[t] = own;
    __syncthreads();
    for (int off = 1; off < 256; off <<= 1) {
        int v = s[t];
        if (t >= off) v += s[t - off];
        __syncthreads();
        s[t] = v;
        __syncthreads();
    }
    if (t < NB_SCAN) bscan[t] = s[t] - own;   // exclusive
}

__global__ void scan3_kernel(const int* __restrict__ deg, const int* __restrict__ bscan,
                             int* __restrict__ row_off, int* __restrict__ wr) {
    __shared__ int s[256];
    int t = threadIdx.x, i = blockIdx.x * 256 + t;
    int own = (i < N_NODES) ? deg[i] : 0;
    s[t] = own;
    __syncthreads();
    for (int off = 1; off < 256; off <<= 1) {
        int v = s[t];
        if (t >= off) v += s[t - off];
        __syncthreads();
        s[t] = v;
        __syncthreads();
    }
    if (i < N_NODES) {
        int ro = bscan[blockIdx.x] + s[t] - own;
        row_off[i] = ro;
        wr[i] = ro;
    }
}

__global__ void fill_kernel(const int* __restrict__ src, const int* __restrict__ dst,
                            int* __restrict__ wr, int* __restrict__ csr_src) {
    int i = blockIdx.x * blockDim.x + threadIdx.x;
    if (i < N_EDGES) {
        int r = atomicAdd(&wr[dst[i]], 1);
        csr_src[r] = src[i];
    }
}

// ---------------------------------------------------------------------------
// Fused layer 1: aggregate from emb (staged in LDS) via per-edge (label,norm),
// then 64x96 register-tiled GEMM.  out = relu(agg@W + b) * out_norm
// ---------------------------------------------------------------------------
__global__ __launch_bounds__(256) void fused_layer1(
        const int2* __restrict__ node_info, const float* __restrict__ emb,
        const int* __restrict__ row_off, const int* __restrict__ deg,
        const int* __restrict__ csr, const float* __restrict__ in_norm,
        const float* __restrict__ W, const float* __restrict__ b,
        const float* __restrict__ post, float* __restrict__ out) {
    constexpr int IN = EMB, INP = EMB + 1, OUT = HID, OUTP = HID, NT = 6, C = EMB / 4;
    __shared__ float emb_s[NLAB][EMB + 4];   // stride 68: labels spread over banks
    __shared__ float in_s[64][INP];
    __shared__ float W_s[IN * OUTP];
    __shared__ float bs[OUTP];
    const int tid = threadIdx.x;
    const int n0 = blockIdx.x * 64;

    for (int idx = tid; idx < NLAB * EMB; idx += 256)
        emb_s[idx >> 6][idx & 63] = emb[idx];
    for (int idx = tid; idx < IN * OUTP; idx += 256)
        W_s[idx] = W[idx];
    if (tid < OUTP) bs[tid] = b[tid];
    __syncthreads();

    // Phase A: aggregate. 64 nodes x 16 float4-chunks = 1024 tasks.
    for (int id = tid; id < 64 * C; id += 256) {
        int m = id / C, c = id - m * C;
        int n = n0 + m;
        float ax = 0.f, ay = 0.f, az = 0.f, aw = 0.f;
        if (n < N_NODES) {
            int k = row_off[n];
            int e = k + deg[n];
            for (; k + 1 < e; k += 2) {
                int s0 = csr[k], s1 = csr[k + 1];
                int2 i0 = node_info[s0];
                int2 i1 = node_info[s1];
                const float4 e0 = *reinterpret_cast<const float4*>(&emb_s[i0.x][c * 4]);
                const float4 e1 = *reinterpret_cast<const float4*>(&emb_s[i1.x][c * 4]);
                float w0 = __int_as_float(i0.y), w1 = __int_as_float(i1.y);
                ax += e0.x * w0 + e1.x * w1; ay += e0.y * w0 + e1.y * w1;
                az += e0.z * w0 + e1.z * w1; aw += e0.w * w0 + e1.w * w1;
            }
            if (k < e) {
                int s0 = csr[k];
                int2 i0 = node_info[s0];
                const float4 e0 = *reinterpret_cast<const float4*>(&emb_s[i0.x][c * 4]);
                float w0 = __int_as_float(i0.y);
                ax += e0.x * w0; ay += e0.y * w0; az += e0.z * w0; aw += e0.w * w0;
            }
            float nn = in_norm[n];
            ax *= nn; ay *= nn; az *= nn; aw *= nn;
        }
        in_s[m][c * 4 + 0] = ax; in_s[m][c * 4 + 1] = ay;
        in_s[m][c * 4 + 2] = az; in_s[m][c * 4 + 3] = aw;
    }
    __syncthreads();

    // Phase B: 64x96 GEMM, 4-node x 6-output register tile per thread.
    const int tx = tid & 15, ty = tid >> 4;
    const int j0 = tx * NT, m0 = ty * 4;
    float acc[4][NT];
#pragma unroll
    for (int i = 0; i < 4; ++i)
#pragma unroll
        for (int jj = 0; jj < NT; ++jj) acc[i][jj] = 0.0f;
#pragma unroll 4
    for (int k = 0; k < IN; ++k) {
        float a[4], w[NT];
#pragma unroll
        for (int i = 0; i < 4; ++i) a[i] = in_s[m0 + i][k];
#pragma unroll
        for (int jj = 0; jj < NT; ++jj) w[jj] = W_s[k * OUTP + j0 + jj];
#pragma unroll
        for (int i = 0; i < 4; ++i)
#pragma unroll
            for (int jj = 0; jj < NT; ++jj) acc[i][jj] += a[i] * w[jj];
    }
#pragma unroll
    for (int i = 0; i < 4; ++i) {
        int n = n0 + m0 + i;
        if (n >= N_NODES) break;
        float pn = post[n];
#pragma unroll
        for (int jj = 0; jj < NT; ++jj) {
            float v = fmaxf(acc[i][jj] + bs[j0 + jj], 0.0f) * pn;
            out[(size_t)n * OUT + j0 + jj] = v;
        }
    }
}

// ---------------------------------------------------------------------------
// Fused layer 2: aggregate from global feature rows (stride 96), then GEMM.
// out = relu(agg@W + b) * out_norm
// ---------------------------------------------------------------------------
__global__ __launch_bounds__(256) void fused_layer2(
        const float* __restrict__ hs, const int* __restrict__ row_off,
        const int* __restrict__ deg, const int* __restrict__ csr,
        const float* __restrict__ in_norm,
        const float* __restrict__ W, const float* __restrict__ b,
        const float* __restrict__ post, float* __restrict__ out) {
    constexpr int IN = HID, INP = HID + 1, OUT = HID, OUTP = HID, NT = 6, C = HID / 4;
    __shared__ float in_s[64][INP];
    __shared__ float W_s[IN * OUTP];
    __shared__ float bs[OUTP];
    const int tid = threadIdx.x;
    const int n0 = blockIdx.x * 64;

    for (int idx = tid; idx < IN * OUTP; idx += 256) W_s[idx] = W[idx];
    if (tid < OUTP) bs[tid] = b[tid];
    __syncthreads();   // W_s ready (in_s filled below before its own barrier)

    // Phase A: aggregate. 64 nodes x 24 float4-chunks = 1536 tasks.
    for (int id = tid; id < 64 * C; id += 256) {
        int m = id / C, c = id - m * C;
        int n = n0 + m;
        float ax = 0.f, ay = 0.f, az = 0.f, aw = 0.f;
        if (n < N_NODES) {
            int k = row_off[n];
            int e = k + deg[n];
            for (; k + 1 < e; k += 2) {
                int s0 = csr[k], s1 = csr[k + 1];
                float4 v0 = *reinterpret_cast<const float4*>(hs + (size_t)s0 * IN + c * 4);
                float4 v1 = *reinterpret_cast<const float4*>(hs + (size_t)s1 * IN + c * 4);
                ax += v0.x + v1.x; ay += v0.y + v1.y;
                az += v0.z + v1.z; aw += v0.w + v1.w;
            }
            if (k < e) {
                int s0 = csr[k];
                float4 v0 = *reinterpret_cast<const float4*>(hs + (size_t)s0 * IN + c * 4);
                ax += v0.x; ay += v0.y; az += v0.z; aw += v0.w;
            }
            float nn = in_norm[n];
            ax *= nn; ay *= nn; az *= nn; aw *= nn;
        }
        in_s[m][c * 4 + 0] = ax; in_s[m][c * 4 + 1] = ay;
        in_s[m][c * 4 + 2] = az; in_s[m][c * 4 + 3] = aw;
    }
    __syncthreads();

    const int tx = tid & 15, ty = tid >> 4;
    const int j0 = tx * NT, m0 = ty * 4;
    float acc[4][NT];
#pragma unroll
    for (int i = 0; i < 4; ++i)
#pragma unroll
        for (int jj = 0; jj < NT; ++jj) acc[i][jj] = 0.0f;
#pragma unroll 4
    for (int k = 0; k < IN; ++k) {
        float a[4], w[NT];
#pragma unroll
        for (int i = 0; i < 4; ++i) a[i] = in_s[m0 + i][k];
#pragma unroll
        for (int jj = 0; jj < NT; ++jj) w[jj] = W_s[k * OUTP + j0 + jj];
#pragma unroll
        for (int i = 0; i < 4; ++i)
#pragma unroll
            for (int jj = 0; jj < NT; ++jj) acc[i][jj] += a[i] * w[jj];
    }
#pragma unroll
    for (int i = 0; i < 4; ++i) {
        int n = n0 + m0 + i;
        if (n >= N_NODES) break;
        float pn = post[n];
#pragma unroll
        for (int jj = 0; jj < NT; ++jj) {
            float v = fmaxf(acc[i][jj] + bs[j0 + jj], 0.0f) * pn;
            out[(size_t)n * OUT + j0 + jj] = v;
        }
    }
}

// Layer-3 transform: t[n, 0..51] = (h2s[n,:] @ W3 | 0 0), row stride TSTRIDE=52.
__global__ __launch_bounds__(256) void linear3_kernel(
        const float* __restrict__ in, const float* __restrict__ W,
        float* __restrict__ out) {
    constexpr int IN = HID, INP = HID + 1, OUT = NLAB, OUTP = 64, NT = 4;
    __shared__ float in_s[64][INP];
    __shared__ float W_s[IN * OUTP];
    const int tid = threadIdx.x;
    const int n0 = blockIdx.x * 64;

    for (int idx = tid; idx < 64 * IN; idx += 256) {
        int m = idx / IN, k = idx - m * IN;
        int n = n0 + m;
        in_s[m][k] = (n < N_NODES) ? in[(size_t)n * IN + k] : 0.0f;
    }
    for (int idx = tid; idx < IN * OUTP; idx += 256) {
        int k = idx / OUTP, j = idx - k * OUTP;
        W_s[idx] = (j < OUT) ? W[k * OUT + j] : 0.0f;
    }
    __syncthreads();

    const int tx = tid & 15, ty = tid >> 4;
    const int j0 = tx * NT, m0 = ty * 4;
    float acc[4][NT];
#pragma unroll
    for (int i = 0; i < 4; ++i)
#pragma unroll
        for (int jj = 0; jj < NT; ++jj) acc[i][jj] = 0.0f;
#pragma unroll 4
    for (int k = 0; k < IN; ++k) {
        float a[4], w[NT];
#pragma unroll
        for (int i = 0; i < 4; ++i) a[i] = in_s[m0 + i][k];
#pragma unroll
        for (int jj = 0; jj < NT; ++jj) w[jj] = W_s[k * OUTP + j0 + jj];
#pragma unroll
        for (int i = 0; i < 4; ++i)
#pragma unroll
            for (int jj = 0; jj < NT; ++jj) acc[i][jj] += a[i] * w[jj];
    }
#pragma unroll
    for (int i = 0; i < 4; ++i) {
        int n = n0 + m0 + i;
        if (n >= N_NODES) break;
#pragma unroll
        for (int jj = 0; jj < NT; ++jj) {
            int j = j0 + jj;
            if (j < TSTRIDE) out[(size_t)n * TSTRIDE + j] = acc[i][jj];  // cols 50,51 = 0
        }
    }
}

// Final gather over t (stride 52): out[n,:50] = in_norm[n]*sum t[src] + b3.
__global__ void gather_out_kernel(const float* __restrict__ t, const int* __restrict__ row_off,
                                  const int* __restrict__ deg, const int* __restrict__ csr,
                                  const float* __restrict__ in_norm, const float* __restrict__ bias,
                                  float* __restrict__ out) {
    constexpr int C = TSTRIDE / 4;  // 13
    int i = blockIdx.x * blockDim.x + threadIdx.x;
    if (i >= N_NODES * C) return;
    int n = i / C;
    int c = i - n * C;
    int k = row_off[n];
    int e = k + deg[n];
    float ax = 0.f, ay = 0.f, az = 0.f, aw = 0.f;
    for (; k + 1 < e; k += 2) {
        int s0 = csr[k], s1 = csr[k + 1];
        float4 v0 = *reinterpret_cast<const float4*>(t + (size_t)s0 * TSTRIDE + c * 4);
        float4 v1 = *reinterpret_cast<const float4*>(t + (size_t)s1 * TSTRIDE + c * 4);
        ax += v0.x + v1.x; ay += v0.y + v1.y; az += v0.z + v1.z; aw += v0.w + v1.w;
    }
    if (k < e) {
        int s0 = csr[k];
        float4 v0 = *reinterpret_cast<const float4*>(t + (size_t)s0 * TSTRIDE + c * 4);
        ax += v0.x; ay += v0.y; az += v0.z; aw += v0.w;
    }
    float nn = in_norm[n];
    int j = c * 4;
    float* op = out + (size_t)n * NLAB + j;   // rows 8B-aligned only -> float2 stores
    float2 lo; lo.x = ax * nn + bias[j];     lo.y = ay * nn + bias[j + 1];
    *reinterpret_cast<float2*>(op) = lo;
    if (j + 2 < NLAB) {  // c<12: cols j+2, j+3 valid
        float2 hi; hi.x = az * nn + bias[j + 2]; hi.y = aw * nn + bias[j + 3];
        *reinterpret_cast<float2*>(op + 2) = hi;
    }
}

static inline int cdiv(long a, int b) { return (int)((a + b - 1) / b); }

extern "C" void kernel_launch(void* const* d_in, const int* in_sizes, int n_in,
                              void* d_out, int out_size, void* d_ws, size_t ws_size,
                              hipStream_t stream) {
    const int*   dep_labels = (const int*)d_in[0];
    const int*   src        = (const int*)d_in[1];
    const int*   dst        = (const int*)d_in[2];
    const float* emb        = (const float*)d_in[3];
    const float* W1 = (const float*)d_in[4]; const float* b1 = (const float*)d_in[5];
    const float* W2 = (const float*)d_in[6]; const float* b2 = (const float*)d_in[7];
    const float* W3 = (const float*)d_in[8]; const float* b3 = (const float*)d_in[9];
    float* out = (float*)d_out;

    // ---- workspace layout ----
    int* wsp        = (int*)d_ws;
    int* deg_out_i  = wsp;                 wsp += N_NODES;
    int* deg_in_i   = wsp;                 wsp += N_NODES;
    int* row_off    = wsp;                 wsp += N_NODES;
    int* wr         = wsp;                 wsp += N_NODES;
    int* bsum       = wsp;                 wsp += 256;
    int* bscan      = wsp;                 wsp += 256;
    int* csr_src    = wsp;                 wsp += N_EDGES;
    float* out_norm = (float*)wsp;         wsp += N_NODES;
    float* in_norm  = (float*)wsp;         wsp += N_NODES;
    int2* node_info = (int2*)wsp;          wsp += 2 * N_NODES;
    float* bufA     = (float*)wsp;         wsp += (size_t)N_NODES * HID;   // h1s / t
    float* bufB     = (float*)wsp;         // h2s (N_NODES*HID)

    const int B = 256;
    const int NLIN = cdiv(N_NODES, 64);    // 782

    hipMemsetAsync(deg_out_i, 0, 2 * N_NODES * sizeof(int), stream);
    deg_kernel<<<cdiv(N_EDGES, B), B, 0, stream>>>(src, dst, deg_out_i, deg_in_i);
    norm_kernel<<<cdiv(N_NODES, B), B, 0, stream>>>(deg_out_i, deg_in_i, dep_labels,
                                                    out_norm, in_norm, node_info);

    scan1_kernel<<<NB_SCAN, 256, 0, stream>>>(deg_in_i, bsum);
    scan2_kernel<<<1, 256, 0, stream>>>(bsum, bscan);
    scan3_kernel<<<NB_SCAN, 256, 0, stream>>>(deg_in_i, bscan, row_off, wr);
    fill_kernel<<<cdiv(N_EDGES, B), B, 0, stream>>>(src, dst, wr, csr_src);

    // Layer 1 (fused): emb-in-LDS aggregate + GEMM 64->96
    fused_layer1<<<NLIN, 256, 0, stream>>>(node_info, emb, row_off, deg_in_i, csr_src,
                                           in_norm, W1, b1, out_norm, bufA);   // bufA = h1s
    // Layer 2 (fused): aggregate from h1s + GEMM 96->96
    fused_layer2<<<NLIN, 256, 0, stream>>>(bufA, row_off, deg_in_i, csr_src,
                                           in_norm, W2, b2, out_norm, bufB);   // bufB = h2s
    // Layer 3: transform first (96->50, stride-52 padded), then gather + bias
    linear3_kernel<<<NLIN, 256, 0, stream>>>(bufB, W3, bufA);                  // bufA = t
    gather_out_kernel<<<cdiv((long)N_NODES * (TSTRIDE / 4), B), B, 0, stream>>>(
        bufA, row_off, deg_in_i, csr_src, in_norm, b3, out);
}

// Round 6
// 384.727 us; speedup vs baseline: 1.1586x; 1.1586x over previous
//
#include <hip/hip_runtime.h>

// GCN 3-layer, CSR-gather (split kernels — fusion regressed: latency-bound
// aggregate needs high occupancy, LDS-heavy GEMM phase killed it in R5).
//   deg+rank (atomic histogram, rank = returned old count) -> scan -> fill
//   (atomic-free via rank) ->
//   L1: agg = in_norm * gather_via(label,out_norm)@emb[L1-resident]; h1s=relu(agg@W1+b1)*out_norm
//   L2: agg = in_norm * gather4<96>(h1s);                            h2s=relu(agg@W2+b2)*out_norm
//   L3: t = h2s@W3 (row stride 52, cols 50/51 = 0); out = in_norm*gather4(t)+b3
#define N_NODES 50000
#define N_EDGES 800000
#define EMB     64
#define HID     96
#define NLAB    50
#define NB_SCAN ((N_NODES + 255) / 256)   // 196
#define TSTRIDE 52                        // padded row stride of t (float4-able)

// Histogram both degrees; rank[i] = old count of dst bucket (unique per edge).
__global__ void deg_rank_kernel(const int* __restrict__ src, const int* __restrict__ dst,
                                int* __restrict__ deg_out, int* __restrict__ deg_in,
                                int* __restrict__ rank) {
    int i = blockIdx.x * blockDim.x + threadIdx.x;
    if (i < N_EDGES) {
        atomicAdd(&deg_out[src[i]], 1);
        rank[i] = atomicAdd(&deg_in[dst[i]], 1);
    }
}

// --- exclusive scan of deg_in -> row_off; also norms + node_info (labels,out_norm) ---
__global__ void scan1_kernel(const int* __restrict__ deg, int* __restrict__ bsum) {
    __shared__ int s[256];
    int t = threadIdx.x, i = blockIdx.x * 256 + t;
    s[t] = (i < N_NODES) ? deg[i] : 0;
    for (int off = 128; off > 0; off >>= 1) {
        __syncthreads();
        if (t < off) s[t] += s[t + off];
    }
    if (t == 0) bsum[blockIdx.x] = s[0];
}

__global__ void scan2_kernel(const int* __restrict__ bsum, int* __restrict__ bscan) {
    __shared__ int s[256];
    int t = threadIdx.x;
    int own = (t < NB_SCAN) ? bsum[t] : 0;
    s[t] = own;
    __syncthreads();
    for (int off = 1; off < 256; off <<= 1) {
        int v = s[t];
        if (t >= off) v += s[t - off];
        __syncthreads();
        s[t] = v;
        __syncthreads();
    }
    if (t < NB_SCAN) bscan[t] = s[t] - own;   // exclusive
}

__global__ void scan3_kernel(const int* __restrict__ deg_in, const int* __restrict__ bscan,
                             const int* __restrict__ deg_out, const int* __restrict__ labels,
                             int* __restrict__ row_off,
                             float* __restrict__ out_norm, float* __restrict__ in_norm,
                             int2* __restrict__ node_info) {
    __shared__ int s[256];
    int t = threadIdx.x, i = blockIdx.x * 256 + t;
    int own = (i < N_NODES) ? deg_in[i] : 0;
    s[t] = own;
    __syncthreads();
    for (int off = 1; off < 256; off <<= 1) {
        int v = s[t];
        if (t >= off) v += s[t - off];
        __syncthreads();
        s[t] = v;
        __syncthreads();
    }
    if (i < N_NODES) {
        row_off[i] = bscan[blockIdx.x] + s[t] - own;
        float on = rsqrtf(fmaxf((float)deg_out[i], 1.0f));
        out_norm[i] = on;
        in_norm[i]  = rsqrtf(fmaxf((float)own, 1.0f));
        node_info[i] = make_int2(labels[i], __float_as_int(on));
    }
}

// Atomic-free CSR fill via precomputed ranks.
__global__ void fill_kernel(const int* __restrict__ src, const int* __restrict__ dst,
                            const int* __restrict__ row_off, const int* __restrict__ rank,
                            int* __restrict__ csr_src) {
    int i = blockIdx.x * blockDim.x + threadIdx.x;
    if (i < N_EDGES) csr_src[row_off[dst[i]] + rank[i]] = src[i];
}

// Layer-1 aggregate straight from emb (12.8 KB, L1-resident) via node_info:
// agg[n, c4] = in_norm[n] * sum_e out_norm[s] * emb[label[s]] (chunk c4)
__global__ void gather1_kernel(const int2* __restrict__ node_info, const float* __restrict__ emb,
                               const int* __restrict__ row_off, const int* __restrict__ deg,
                               const int* __restrict__ csr, const float* __restrict__ in_norm,
                               float* __restrict__ agg) {
    constexpr int C = EMB / 4;   // 16
    int i = blockIdx.x * blockDim.x + threadIdx.x;
    if (i >= N_NODES * C) return;
    int n = i / C;
    int c = i - n * C;
    int k = row_off[n];
    int e = k + deg[n];
    float ax = 0.f, ay = 0.f, az = 0.f, aw = 0.f;
    for (; k + 1 < e; k += 2) {
        int s0 = csr[k], s1 = csr[k + 1];
        int2 i0 = node_info[s0];
        int2 i1 = node_info[s1];
        float4 e0 = *reinterpret_cast<const float4*>(emb + i0.x * EMB + c * 4);
        float4 e1 = *reinterpret_cast<const float4*>(emb + i1.x * EMB + c * 4);
        float w0 = __int_as_float(i0.y), w1 = __int_as_float(i1.y);
        ax += e0.x * w0 + e1.x * w1; ay += e0.y * w0 + e1.y * w1;
        az += e0.z * w0 + e1.z * w1; aw += e0.w * w0 + e1.w * w1;
    }
    if (k < e) {
        int2 i0 = node_info[csr[k]];
        float4 e0 = *reinterpret_cast<const float4*>(emb + i0.x * EMB + c * 4);
        float w0 = __int_as_float(i0.y);
        ax += e0.x * w0; ay += e0.y * w0; az += e0.z * w0; aw += e0.w * w0;
    }
    float nn = in_norm[n];
    float4 r; r.x = ax * nn; r.y = ay * nn; r.z = az * nn; r.w = aw * nn;
    *reinterpret_cast<float4*>(agg + (size_t)n * EMB + c * 4) = r;
}

// float4 gather over stride-D rows: agg[n,c4] = in_norm[n] * sum hs[csr[k]] chunk c4
template <int D>
__global__ void gather4_kernel(const float* __restrict__ hs, const int* __restrict__ row_off,
                               const int* __restrict__ deg, const int* __restrict__ csr,
                               const float* __restrict__ in_norm, float* __restrict__ out) {
    constexpr int C = D / 4;
    int i = blockIdx.x * blockDim.x + threadIdx.x;
    if (i >= N_NODES * C) return;
    int n = i / C;
    int c = i - n * C;
    int k = row_off[n];
    int e = k + deg[n];
    float ax = 0.f, ay = 0.f, az = 0.f, aw = 0.f;
    for (; k + 1 < e; k += 2) {
        int s0 = csr[k], s1 = csr[k + 1];
        float4 v0 = *reinterpret_cast<const float4*>(hs + (size_t)s0 * D + c * 4);
        float4 v1 = *reinterpret_cast<const float4*>(hs + (size_t)s1 * D + c * 4);
        ax += v0.x + v1.x; ay += v0.y + v1.y; az += v0.z + v1.z; aw += v0.w + v1.w;
    }
    if (k < e) {
        float4 v0 = *reinterpret_cast<const float4*>(hs + (size_t)csr[k] * D + c * 4);
        ax += v0.x; ay += v0.y; az += v0.z; aw += v0.w;
    }
    float nn = in_norm[n];
    float4 r; r.x = ax * nn; r.y = ay * nn; r.z = az * nn; r.w = aw * nn;
    *reinterpret_cast<float4*>(out + (size_t)n * D + c * 4) = r;
}

// Register-tiled linear: 64 nodes x OUTP outputs per block, 4x NT per thread.
// out[n,j] = act(in[n,:]@W + b[j]) * post[n]; row stride OSTRIDE (j<OSTRIDE written).
template <int IN, int INP, int OUT, int OUTP, int NT, int OSTRIDE, bool RELU>
__global__ __launch_bounds__(256) void linear_tiled(
        const float* __restrict__ in, const float* __restrict__ W,
        const float* __restrict__ b, const float* __restrict__ post,
        float* __restrict__ out) {
    __shared__ float in_s[64][INP];      // INP odd -> conflict-free column reads
    __shared__ float W_s[IN * OUTP];
    __shared__ float bs[OUTP];
    const int tid = threadIdx.x;
    const int n0 = blockIdx.x * 64;

    for (int idx = tid; idx < 64 * IN; idx += 256) {
        int m = idx / IN, k = idx - m * IN;
        int n = n0 + m;
        in_s[m][k] = (n < N_NODES) ? in[(size_t)n * IN + k] : 0.0f;
    }
    for (int idx = tid; idx < IN * OUTP; idx += 256) {
        int k = idx / OUTP, j = idx - k * OUTP;
        W_s[idx] = (j < OUT) ? W[k * OUT + j] : 0.0f;
    }
    if (tid < OUTP) bs[tid] = (b && tid < OUT) ? b[tid] : 0.0f;
    __syncthreads();

    const int tx = tid & 15, ty = tid >> 4;
    const int j0 = tx * NT, m0 = ty * 4;
    float acc[4][NT];
#pragma unroll
    for (int i = 0; i < 4; ++i)
#pragma unroll
        for (int jj = 0; jj < NT; ++jj) acc[i][jj] = 0.0f;
#pragma unroll 4
    for (int k = 0; k < IN; ++k) {
        float a[4], w[NT];
#pragma unroll
        for (int i = 0; i < 4; ++i) a[i] = in_s[m0 + i][k];
#pragma unroll
        for (int jj = 0; jj < NT; ++jj) w[jj] = W_s[k * OUTP + j0 + jj];
#pragma unroll
        for (int i = 0; i < 4; ++i)
#pragma unroll
            for (int jj = 0; jj < NT; ++jj) acc[i][jj] += a[i] * w[jj];
    }
#pragma unroll
    for (int i = 0; i < 4; ++i) {
        int n = n0 + m0 + i;
        if (n >= N_NODES) break;
        float pn = post ? post[n] : 1.0f;
#pragma unroll
        for (int jj = 0; jj < NT; ++jj) {
            int j = j0 + jj;
            if (j < OSTRIDE) {
                float v = acc[i][jj] + bs[j0 + jj];
                if (RELU) v = fmaxf(v, 0.0f);
                out[(size_t)n * OSTRIDE + j] = v * pn;
            }
        }
    }
}

// Final gather over t (stride 52): out[n,:50] = in_norm[n]*sum t[src] + b3.
__global__ void gather_out_kernel(const float* __restrict__ t, const int* __restrict__ row_off,
                                  const int* __restrict__ deg, const int* __restrict__ csr,
                                  const float* __restrict__ in_norm, const float* __restrict__ bias,
                                  float* __restrict__ out) {
    constexpr int C = TSTRIDE / 4;  // 13
    int i = blockIdx.x * blockDim.x + threadIdx.x;
    if (i >= N_NODES * C) return;
    int n = i / C;
    int c = i - n * C;
    int k = row_off[n];
    int e = k + deg[n];
    float ax = 0.f, ay = 0.f, az = 0.f, aw = 0.f;
    for (; k + 1 < e; k += 2) {
        int s0 = csr[k], s1 = csr[k + 1];
        float4 v0 = *reinterpret_cast<const float4*>(t + (size_t)s0 * TSTRIDE + c * 4);
        float4 v1 = *reinterpret_cast<const float4*>(t + (size_t)s1 * TSTRIDE + c * 4);
        ax += v0.x + v1.x; ay += v0.y + v1.y; az += v0.z + v1.z; aw += v0.w + v1.w;
    }
    if (k < e) {
        float4 v0 = *reinterpret_cast<const float4*>(t + (size_t)csr[k] * TSTRIDE + c * 4);
        ax += v0.x; ay += v0.y; az += v0.z; aw += v0.w;
    }
    float nn = in_norm[n];
    int j = c * 4;
    float* op = out + (size_t)n * NLAB + j;   // rows 8B-aligned only -> float2 stores
    float2 lo; lo.x = ax * nn + bias[j];     lo.y = ay * nn + bias[j + 1];
    *reinterpret_cast<float2*>(op) = lo;
    if (j + 2 < NLAB) {
        float2 hi; hi.x = az * nn + bias[j + 2]; hi.y = aw * nn + bias[j + 3];
        *reinterpret_cast<float2*>(op + 2) = hi;
    }
}

static inline int cdiv(long a, int b) { return (int)((a + b - 1) / b); }

extern "C" void kernel_launch(void* const* d_in, const int* in_sizes, int n_in,
                              void* d_out, int out_size, void* d_ws, size_t ws_size,
                              hipStream_t stream) {
    const int*   dep_labels = (const int*)d_in[0];
    const int*   src        = (const int*)d_in[1];
    const int*   dst        = (const int*)d_in[2];
    const float* emb        = (const float*)d_in[3];
    const float* W1 = (const float*)d_in[4]; const float* b1 = (const float*)d_in[5];
    const float* W2 = (const float*)d_in[6]; const float* b2 = (const float*)d_in[7];
    const float* W3 = (const float*)d_in[8]; const float* b3 = (const float*)d_in[9];
    float* out = (float*)d_out;

    // ---- workspace layout ----
    int* wsp        = (int*)d_ws;
    int* deg_out_i  = wsp;                 wsp += N_NODES;
    int* deg_in_i   = wsp;                 wsp += N_NODES;
    int* row_off    = wsp;                 wsp += N_NODES;
    int* rank       = wsp;                 wsp += N_EDGES;
    int* bsum       = wsp;                 wsp += 256;
    int* bscan      = wsp;                 wsp += 256;
    int* csr_src    = wsp;                 wsp += N_EDGES;
    float* out_norm = (float*)wsp;         wsp += N_NODES;
    float* in_norm  = (float*)wsp;         wsp += N_NODES;
    int2* node_info = (int2*)wsp;          wsp += 2 * N_NODES;
    float* bufA     = (float*)wsp;         wsp += (size_t)N_NODES * HID;   // agg / t
    float* bufB     = (float*)wsp;         // h1s / h2s (N_NODES*HID)

    const int B = 256;
    const int NLIN = cdiv(N_NODES, 64);    // 782

    hipMemsetAsync(deg_out_i, 0, 2 * N_NODES * sizeof(int), stream);
    deg_rank_kernel<<<cdiv(N_EDGES, B), B, 0, stream>>>(src, dst, deg_out_i, deg_in_i, rank);

    scan1_kernel<<<NB_SCAN, 256, 0, stream>>>(deg_in_i, bsum);
    scan2_kernel<<<1, 256, 0, stream>>>(bsum, bscan);
    scan3_kernel<<<NB_SCAN, 256, 0, stream>>>(deg_in_i, bscan, deg_out_i, dep_labels,
                                              row_off, out_norm, in_norm, node_info);
    fill_kernel<<<cdiv(N_EDGES, B), B, 0, stream>>>(src, dst, row_off, rank, csr_src);

    // Layer 1: gather via (label,out_norm) from L1-resident emb -> linear 64->96
    gather1_kernel<<<cdiv((long)N_NODES * (EMB / 4), B), B, 0, stream>>>(
        node_info, emb, row_off, deg_in_i, csr_src, in_norm, bufA);
    linear_tiled<EMB, EMB + 1, HID, HID, 6, HID, true><<<NLIN, 256, 0, stream>>>(
        bufA, W1, b1, out_norm, bufB);          // bufB = h1s

    // Layer 2: gather4<96> -> linear 96->96
    gather4_kernel<HID><<<cdiv((long)N_NODES * (HID / 4), B), B, 0, stream>>>(
        bufB, row_off, deg_in_i, csr_src, in_norm, bufA);
    linear_tiled<HID, HID + 1, HID, HID, 6, HID, true><<<NLIN, 256, 0, stream>>>(
        bufA, W2, b2, out_norm, bufB);          // bufB = h2s

    // Layer 3: transform first (96->50, stride-52 padded with zero cols), then gather+bias
    linear_tiled<HID, HID + 1, NLAB, 64, 4, TSTRIDE, false><<<NLIN, 256, 0, stream>>>(
        bufB, W3, nullptr, nullptr, bufA);      // bufA = t
    gather_out_kernel<<<cdiv((long)N_NODES * (TSTRIDE / 4), B), B, 0, stream>>>(
        bufA, row_off, deg_in_i, csr_src, in_norm, b3, out);
}

// Round 7
// 365.827 us; speedup vs baseline: 1.2184x; 1.0517x over previous
//
#include <hip/hip_runtime.h>

// GCN 3-layer, CSR-gather, low-rank layer-1 fusion:
//   deg+rank (atomic histogram; rank = returned old count) -> scan -> fill ->
//   T1 = emb@W1 (50x96, L1-resident) ->
//   L1 fused: h1s[n] = relu(in_norm[n]*sum_s w_s*T1[lbl_s] + b1) * out_norm[n]
//   L2: agg = in_norm * gather4<96>(h1s); h2s = relu(agg@W2+b2)*out_norm
//   L3: t = h2s@W3 (row stride 52, cols 50/51 = 0); out = in_norm*gather4(t)+b3
#define N_NODES 50000
#define N_EDGES 800000
#define EMB     64
#define HID     96
#define NLAB    50
#define NB_SCAN ((N_NODES + 255) / 256)   // 196
#define TSTRIDE 52                        // padded row stride of t (float4-able)

// Histogram both degrees; rank[i] = old count of dst bucket (unique per edge).
__global__ void deg_rank_kernel(const int* __restrict__ src, const int* __restrict__ dst,
                                int* __restrict__ deg_out, int* __restrict__ deg_in,
                                int* __restrict__ rank) {
    int i = blockIdx.x * blockDim.x + threadIdx.x;
    if (i < N_EDGES) {
        atomicAdd(&deg_out[src[i]], 1);
        rank[i] = atomicAdd(&deg_in[dst[i]], 1);
    }
}

// T1[l][j] = sum_k emb[l,k] * W1[k,j]   (50 x 96)
__global__ void t1_kernel(const float* __restrict__ emb, const float* __restrict__ W1,
                          float* __restrict__ T1) {
    int i = blockIdx.x * blockDim.x + threadIdx.x;
    if (i >= NLAB * HID) return;
    int l = i / HID, j = i - l * HID;
    float s = 0.0f;
#pragma unroll
    for (int k = 0; k < EMB; ++k) s += emb[l * EMB + k] * W1[k * HID + j];
    T1[i] = s;
}

// --- exclusive scan of deg_in -> row_off; also norms + node_info ---
__global__ void scan1_kernel(const int* __restrict__ deg, int* __restrict__ bsum) {
    __shared__ int s[256];
    int t = threadIdx.x, i = blockIdx.x * 256 + t;
    s[t] = (i < N_NODES) ? deg[i] : 0;
    for (int off = 128; off > 0; off >>= 1) {
        __syncthreads();
        if (t < off) s[t] += s[t + off];
    }
    if (t == 0) bsum[blockIdx.x] = s[0];
}

__global__ void scan2_kernel(const int* __restrict__ bsum, int* __restrict__ bscan) {
    __shared__ int s[256];
    int t = threadIdx.x;
    int own = (t < NB_SCAN) ? bsum[t] : 0;
    s[t] = own;
    __syncthreads();
    for (int off = 1; off < 256; off <<= 1) {
        int v = s[t];
        if (t >= off) v += s[t - off];
        __syncthreads();
        s[t] = v;
        __syncthreads();
    }
    if (t < NB_SCAN) bscan[t] = s[t] - own;   // exclusive
}

__global__ void scan3_kernel(const int* __restrict__ deg_in, const int* __restrict__ bscan,
                             const int* __restrict__ deg_out, const int* __restrict__ labels,
                             int* __restrict__ row_off,
                             float* __restrict__ out_norm, float* __restrict__ in_norm,
                             int2* __restrict__ node_info) {
    __shared__ int s[256];
    int t = threadIdx.x, i = blockIdx.x * 256 + t;
    int own = (i < N_NODES) ? deg_in[i] : 0;
    s[t] = own;
    __syncthreads();
    for (int off = 1; off < 256; off <<= 1) {
        int v = s[t];
        if (t >= off) v += s[t - off];
        __syncthreads();
        s[t] = v;
        __syncthreads();
    }
    if (i < N_NODES) {
        row_off[i] = bscan[blockIdx.x] + s[t] - own;
        float on = rsqrtf(fmaxf((float)deg_out[i], 1.0f));
        out_norm[i] = on;
        in_norm[i]  = rsqrtf(fmaxf((float)own, 1.0f));
        node_info[i] = make_int2(labels[i], __float_as_int(on));
    }
}

// Atomic-free CSR fill via precomputed ranks.
__global__ void fill_kernel(const int* __restrict__ src, const int* __restrict__ dst,
                            const int* __restrict__ row_off, const int* __restrict__ rank,
                            int* __restrict__ csr_src) {
    int i = blockIdx.x * blockDim.x + threadIdx.x;
    if (i < N_EDGES) csr_src[row_off[dst[i]] + rank[i]] = src[i];
}

// Fused layer 1: h1s[n,c4] = relu(in_norm[n]*sum_e w_s*T1[lbl_s][c4] + b1) * out_norm[n]
__global__ void gather1t_kernel(const int2* __restrict__ node_info, const float* __restrict__ T1,
                                const int* __restrict__ row_off, const int* __restrict__ deg,
                                const int* __restrict__ csr, const float* __restrict__ in_norm,
                                const float* __restrict__ out_norm, const float* __restrict__ b1,
                                float* __restrict__ h1s) {
    constexpr int C = HID / 4;   // 24
    int i = blockIdx.x * blockDim.x + threadIdx.x;
    if (i >= N_NODES * C) return;
    int n = i / C;
    int c = i - n * C;
    int k = row_off[n];
    int e = k + deg[n];
    float ax = 0.f, ay = 0.f, az = 0.f, aw = 0.f;
    for (; k + 3 < e; k += 4) {
        int2 i0 = node_info[csr[k]];
        int2 i1 = node_info[csr[k + 1]];
        int2 i2 = node_info[csr[k + 2]];
        int2 i3 = node_info[csr[k + 3]];
        float4 t0 = *reinterpret_cast<const float4*>(T1 + i0.x * HID + c * 4);
        float4 t1 = *reinterpret_cast<const float4*>(T1 + i1.x * HID + c * 4);
        float4 t2 = *reinterpret_cast<const float4*>(T1 + i2.x * HID + c * 4);
        float4 t3 = *reinterpret_cast<const float4*>(T1 + i3.x * HID + c * 4);
        float w0 = __int_as_float(i0.y), w1 = __int_as_float(i1.y);
        float w2 = __int_as_float(i2.y), w3 = __int_as_float(i3.y);
        ax += t0.x * w0 + t1.x * w1 + t2.x * w2 + t3.x * w3;
        ay += t0.y * w0 + t1.y * w1 + t2.y * w2 + t3.y * w3;
        az += t0.z * w0 + t1.z * w1 + t2.z * w2 + t3.z * w3;
        aw += t0.w * w0 + t1.w * w1 + t2.w * w2 + t3.w * w3;
    }
    for (; k < e; ++k) {
        int2 i0 = node_info[csr[k]];
        float4 t0 = *reinterpret_cast<const float4*>(T1 + i0.x * HID + c * 4);
        float w0 = __int_as_float(i0.y);
        ax += t0.x * w0; ay += t0.y * w0; az += t0.z * w0; aw += t0.w * w0;
    }
    float nn = in_norm[n];
    float on = out_norm[n];
    float4 bb = *reinterpret_cast<const float4*>(b1 + c * 4);
    float4 r;
    r.x = fmaxf(ax * nn + bb.x, 0.0f) * on;
    r.y = fmaxf(ay * nn + bb.y, 0.0f) * on;
    r.z = fmaxf(az * nn + bb.z, 0.0f) * on;
    r.w = fmaxf(aw * nn + bb.w, 0.0f) * on;
    *reinterpret_cast<float4*>(h1s + (size_t)n * HID + c * 4) = r;
}

// float4 gather over stride-D rows: out[n,c4] = in_norm[n] * sum hs[csr[k]] chunk c4
template <int D>
__global__ void gather4_kernel(const float* __restrict__ hs, const int* __restrict__ row_off,
                               const int* __restrict__ deg, const int* __restrict__ csr,
                               const float* __restrict__ in_norm, float* __restrict__ out) {
    constexpr int C = D / 4;
    int i = blockIdx.x * blockDim.x + threadIdx.x;
    if (i >= N_NODES * C) return;
    int n = i / C;
    int c = i - n * C;
    int k = row_off[n];
    int e = k + deg[n];
    float ax = 0.f, ay = 0.f, az = 0.f, aw = 0.f;
    for (; k + 3 < e; k += 4) {
        int s0 = csr[k], s1 = csr[k + 1], s2 = csr[k + 2], s3 = csr[k + 3];
        float4 v0 = *reinterpret_cast<const float4*>(hs + (size_t)s0 * D + c * 4);
        float4 v1 = *reinterpret_cast<const float4*>(hs + (size_t)s1 * D + c * 4);
        float4 v2 = *reinterpret_cast<const float4*>(hs + (size_t)s2 * D + c * 4);
        float4 v3 = *reinterpret_cast<const float4*>(hs + (size_t)s3 * D + c * 4);
        ax += (v0.x + v1.x) + (v2.x + v3.x);
        ay += (v0.y + v1.y) + (v2.y + v3.y);
        az += (v0.z + v1.z) + (v2.z + v3.z);
        aw += (v0.w + v1.w) + (v2.w + v3.w);
    }
    for (; k < e; ++k) {
        float4 v0 = *reinterpret_cast<const float4*>(hs + (size_t)csr[k] * D + c * 4);
        ax += v0.x; ay += v0.y; az += v0.z; aw += v0.w;
    }
    float nn = in_norm[n];
    float4 r; r.x = ax * nn; r.y = ay * nn; r.z = az * nn; r.w = aw * nn;
    *reinterpret_cast<float4*>(out + (size_t)n * D + c * 4) = r;
}

// Register-tiled linear: 64 nodes x OUTP outputs per block, 4x NT per thread.
template <int IN, int INP, int OUT, int OUTP, int NT, int OSTRIDE, bool RELU>
__global__ __launch_bounds__(256) void linear_tiled(
        const float* __restrict__ in, const float* __restrict__ W,
        const float* __restrict__ b, const float* __restrict__ post,
        float* __restrict__ out) {
    __shared__ float in_s[64][INP];      // INP odd -> conflict-free column reads
    __shared__ float W_s[IN * OUTP];
    __shared__ float bs[OUTP];
    const int tid = threadIdx.x;
    const int n0 = blockIdx.x * 64;

    for (int idx = tid; idx < 64 * IN; idx += 256) {
        int m = idx / IN, k = idx - m * IN;
        int n = n0 + m;
        in_s[m][k] = (n < N_NODES) ? in[(size_t)n * IN + k] : 0.0f;
    }
    for (int idx = tid; idx < IN * OUTP; idx += 256) {
        int k = idx / OUTP, j = idx - k * OUTP;
        W_s[idx] = (j < OUT) ? W[k * OUT + j] : 0.0f;
    }
    if (tid < OUTP) bs[tid] = (b && tid < OUT) ? b[tid] : 0.0f;
    __syncthreads();

    const int tx = tid & 15, ty = tid >> 4;
    const int j0 = tx * NT, m0 = ty * 4;
    float acc[4][NT];
#pragma unroll
    for (int i = 0; i < 4; ++i)
#pragma unroll
        for (int jj = 0; jj < NT; ++jj) acc[i][jj] = 0.0f;
#pragma unroll 4
    for (int k = 0; k < IN; ++k) {
        float a[4], w[NT];
#pragma unroll
        for (int i = 0; i < 4; ++i) a[i] = in_s[m0 + i][k];
#pragma unroll
        for (int jj = 0; jj < NT; ++jj) w[jj] = W_s[k * OUTP + j0 + jj];
#pragma unroll
        for (int i = 0; i < 4; ++i)
#pragma unroll
            for (int jj = 0; jj < NT; ++jj) acc[i][jj] += a[i] * w[jj];
    }
#pragma unroll
    for (int i = 0; i < 4; ++i) {
        int n = n0 + m0 + i;
        if (n >= N_NODES) break;
        float pn = post ? post[n] : 1.0f;
#pragma unroll
        for (int jj = 0; jj < NT; ++jj) {
            int j = j0 + jj;
            if (j < OSTRIDE) {
                float v = acc[i][jj] + bs[j0 + jj];
                if (RELU) v = fmaxf(v, 0.0f);
                out[(size_t)n * OSTRIDE + j] = v * pn;
            }
        }
    }
}

// Final gather over t (stride 52): out[n,:50] = in_norm[n]*sum t[src] + b3.
__global__ void gather_out_kernel(const float* __restrict__ t, const int* __restrict__ row_off,
                                  const int* __restrict__ deg, const int* __restrict__ csr,
                                  const float* __restrict__ in_norm, const float* __restrict__ bias,
                                  float* __restrict__ out) {
    constexpr int C = TSTRIDE / 4;  // 13
    int i = blockIdx.x * blockDim.x + threadIdx.x;
    if (i >= N_NODES * C) return;
    int n = i / C;
    int c = i - n * C;
    int k = row_off[n];
    int e = k + deg[n];
    float ax = 0.f, ay = 0.f, az = 0.f, aw = 0.f;
    for (; k + 3 < e; k += 4) {
        int s0 = csr[k], s1 = csr[k + 1], s2 = csr[k + 2], s3 = csr[k + 3];
        float4 v0 = *reinterpret_cast<const float4*>(t + (size_t)s0 * TSTRIDE + c * 4);
        float4 v1 = *reinterpret_cast<const float4*>(t + (size_t)s1 * TSTRIDE + c * 4);
        float4 v2 = *reinterpret_cast<const float4*>(t + (size_t)s2 * TSTRIDE + c * 4);
        float4 v3 = *reinterpret_cast<const float4*>(t + (size_t)s3 * TSTRIDE + c * 4);
        ax += (v0.x + v1.x) + (v2.x + v3.x);
        ay += (v0.y + v1.y) + (v2.y + v3.y);
        az += (v0.z + v1.z) + (v2.z + v3.z);
        aw += (v0.w + v1.w) + (v2.w + v3.w);
    }
    for (; k < e; ++k) {
        float4 v0 = *reinterpret_cast<const float4*>(t + (size_t)csr[k] * TSTRIDE + c * 4);
        ax += v0.x; ay += v0.y; az += v0.z; aw += v0.w;
    }
    float nn = in_norm[n];
    int j = c * 4;
    float* op = out + (size_t)n * NLAB + j;   // rows 8B-aligned only -> float2 stores
    float2 lo; lo.x = ax * nn + bias[j];     lo.y = ay * nn + bias[j + 1];
    *reinterpret_cast<float2*>(op) = lo;
    if (j + 2 < NLAB) {
        float2 hi; hi.x = az * nn + bias[j + 2]; hi.y = aw * nn + bias[j + 3];
        *reinterpret_cast<float2*>(op + 2) = hi;
    }
}

static inline int cdiv(long a, int b) { return (int)((a + b - 1) / b); }

extern "C" void kernel_launch(void* const* d_in, const int* in_sizes, int n_in,
                              void* d_out, int out_size, void* d_ws, size_t ws_size,
                              hipStream_t stream) {
    const int*   dep_labels = (const int*)d_in[0];
    const int*   src        = (const int*)d_in[1];
    const int*   dst        = (const int*)d_in[2];
    const float* emb        = (const float*)d_in[3];
    const float* W1 = (const float*)d_in[4]; const float* b1 = (const float*)d_in[5];
    const float* W2 = (const float*)d_in[6]; const float* b2 = (const float*)d_in[7];
    const float* W3 = (const float*)d_in[8]; const float* b3 = (const float*)d_in[9];
    float* out = (float*)d_out;

    // ---- workspace layout ----
    int* wsp        = (int*)d_ws;
    int* deg_out_i  = wsp;                 wsp += N_NODES;
    int* deg_in_i   = wsp;                 wsp += N_NODES;
    int* row_off    = wsp;                 wsp += N_NODES;
    int* rank       = wsp;                 wsp += N_EDGES;
    int* bsum       = wsp;                 wsp += 256;
    int* bscan      = wsp;                 wsp += 256;
    int* csr_src    = wsp;                 wsp += N_EDGES;
    float* out_norm = (float*)wsp;         wsp += N_NODES;
    float* in_norm  = (float*)wsp;         wsp += N_NODES;
    int2* node_info = (int2*)wsp;          wsp += 2 * N_NODES;
    float* T1       = (float*)wsp;         wsp += NLAB * HID;
    float* bufA     = (float*)wsp;         wsp += (size_t)N_NODES * HID;   // agg / t
    float* bufB     = (float*)wsp;         // h1s / h2s (N_NODES*HID)

    const int B = 256;
    const int NLIN = cdiv(N_NODES, 64);    // 782

    hipMemsetAsync(deg_out_i, 0, 2 * N_NODES * sizeof(int), stream);
    deg_rank_kernel<<<cdiv(N_EDGES, B), B, 0, stream>>>(src, dst, deg_out_i, deg_in_i, rank);
    t1_kernel<<<cdiv(NLAB * HID, B), B, 0, stream>>>(emb, W1, T1);

    scan1_kernel<<<NB_SCAN, 256, 0, stream>>>(deg_in_i, bsum);
    scan2_kernel<<<1, 256, 0, stream>>>(bsum, bscan);
    scan3_kernel<<<NB_SCAN, 256, 0, stream>>>(deg_in_i, bscan, deg_out_i, dep_labels,
                                              row_off, out_norm, in_norm, node_info);
    fill_kernel<<<cdiv(N_EDGES, B), B, 0, stream>>>(src, dst, row_off, rank, csr_src);

    // Layer 1 fused: gather over T1 (L1-resident) with relu/bias/norm epilogue
    gather1t_kernel<<<cdiv((long)N_NODES * (HID / 4), B), B, 0, stream>>>(
        node_info, T1, row_off, deg_in_i, csr_src, in_norm, out_norm, b1, bufB); // bufB = h1s

    // Layer 2: gather4<96> -> linear 96->96
    gather4_kernel<HID><<<cdiv((long)N_NODES * (HID / 4), B), B, 0, stream>>>(
        bufB, row_off, deg_in_i, csr_src, in_norm, bufA);
    linear_tiled<HID, HID + 1, HID, HID, 6, HID, true><<<NLIN, 256, 0, stream>>>(
        bufA, W2, b2, out_norm, bufB);          // bufB = h2s

    // Layer 3: transform first (96->50, stride-52 padded with zero cols), then gather+bias
    linear_tiled<HID, HID + 1, NLAB, 64, 4, TSTRIDE, false><<<NLIN, 256, 0, stream>>>(
        bufB, W3, nullptr, nullptr, bufA);      // bufA = t
    gather_out_kernel<<<cdiv((long)N_NODES * (TSTRIDE / 4), B), B, 0, stream>>>(
        bufA, row_off, deg_in_i, csr_src, in_norm, b3, out);
}

// Round 8
// 325.895 us; speedup vs baseline: 1.3677x; 1.1225x over previous
//
#include <hip/hip_runtime.h>

// GCN 3-layer, CSR-gather, low-rank L1 + fused L2/L3 transform:
//   deg+rank (atomic histogram; ~78us = fabric-atomic floor) -> scan -> fill ->
//   T1 = emb@W1 (50x96, L1-resident) ->
//   L1 fused: h1s[n] = relu(in_norm[n]*sum_s w_s*T1[lbl_s] + b1) * out_norm[n]
//   L2 agg:  agg = in_norm * gather(h1s)            [2 chunks/thread, unroll 4]
//   L2+L3 fused GEMM: h2 = relu(agg@W2+b2)*out_norm (LDS-resident), t = h2@W3
//   L3: out = in_norm*gather(t, stride 52) + b3
#define N_NODES 50000
#define N_EDGES 800000
#define EMB     64
#define HID     96
#define NLAB    50
#define NB_SCAN ((N_NODES + 255) / 256)   // 196
#define TSTRIDE 52                        // padded row stride of t (float4-able)

// Histogram both degrees; rank[i] = old count of dst bucket (unique per edge).
__global__ void deg_rank_kernel(const int* __restrict__ src, const int* __restrict__ dst,
                                int* __restrict__ deg_out, int* __restrict__ deg_in,
                                int* __restrict__ rank) {
    int i = blockIdx.x * blockDim.x + threadIdx.x;
    if (i < N_EDGES) {
        atomicAdd(&deg_out[src[i]], 1);
        rank[i] = atomicAdd(&deg_in[dst[i]], 1);
    }
}

// T1[l][j] = sum_k emb[l,k] * W1[k,j]   (50 x 96)
__global__ void t1_kernel(const float* __restrict__ emb, const float* __restrict__ W1,
                          float* __restrict__ T1) {
    int i = blockIdx.x * blockDim.x + threadIdx.x;
    if (i >= NLAB * HID) return;
    int l = i / HID, j = i - l * HID;
    float s = 0.0f;
#pragma unroll
    for (int k = 0; k < EMB; ++k) s += emb[l * EMB + k] * W1[k * HID + j];
    T1[i] = s;
}

// --- exclusive scan of deg_in -> row_off; also norms + node_info ---
__global__ void scan1_kernel(const int* __restrict__ deg, int* __restrict__ bsum) {
    __shared__ int s[256];
    int t = threadIdx.x, i = blockIdx.x * 256 + t;
    s[t] = (i < N_NODES) ? deg[i] : 0;
    for (int off = 128; off > 0; off >>= 1) {
        __syncthreads();
        if (t < off) s[t] += s[t + off];
    }
    if (t == 0) bsum[blockIdx.x] = s[0];
}

__global__ void scan2_kernel(const int* __restrict__ bsum, int* __restrict__ bscan) {
    __shared__ int s[256];
    int t = threadIdx.x;
    int own = (t < NB_SCAN) ? bsum[t] : 0;
    s[t] = own;
    __syncthreads();
    for (int off = 1; off < 256; off <<= 1) {
        int v = s[t];
        if (t >= off) v += s[t - off];
        __syncthreads();
        s[t] = v;
        __syncthreads();
    }
    if (t < NB_SCAN) bscan[t] = s[t] - own;   // exclusive
}

__global__ void scan3_kernel(const int* __restrict__ deg_in, const int* __restrict__ bscan,
                             const int* __restrict__ deg_out, const int* __restrict__ labels,
                             int* __restrict__ row_off,
                             float* __restrict__ out_norm, float* __restrict__ in_norm,
                             int2* __restrict__ node_info) {
    __shared__ int s[256];
    int t = threadIdx.x, i = blockIdx.x * 256 + t;
    int own = (i < N_NODES) ? deg_in[i] : 0;
    s[t] = own;
    __syncthreads();
    for (int off = 1; off < 256; off <<= 1) {
        int v = s[t];
        if (t >= off) v += s[t - off];
        __syncthreads();
        s[t] = v;
        __syncthreads();
    }
    if (i < N_NODES) {
        row_off[i] = bscan[blockIdx.x] + s[t] - own;
        float on = rsqrtf(fmaxf((float)deg_out[i], 1.0f));
        out_norm[i] = on;
        in_norm[i]  = rsqrtf(fmaxf((float)own, 1.0f));
        node_info[i] = make_int2(labels[i], __float_as_int(on));
    }
}

// Atomic-free CSR fill via precomputed ranks.
__global__ void fill_kernel(const int* __restrict__ src, const int* __restrict__ dst,
                            const int* __restrict__ row_off, const int* __restrict__ rank,
                            int* __restrict__ csr_src) {
    int i = blockIdx.x * blockDim.x + threadIdx.x;
    if (i < N_EDGES) csr_src[row_off[dst[i]] + rank[i]] = src[i];
}

// Fused layer 1: 2 float4 chunks per thread (c and c+12), unroll-4 edges.
// h1s[n,:] = relu(in_norm[n]*sum_e w_s*T1[lbl_s] + b1) * out_norm[n]
__global__ void gather1t_kernel(const int2* __restrict__ node_info, const float* __restrict__ T1,
                                const int* __restrict__ row_off, const int* __restrict__ deg,
                                const int* __restrict__ csr, const float* __restrict__ in_norm,
                                const float* __restrict__ out_norm, const float* __restrict__ b1,
                                float* __restrict__ h1s) {
    constexpr int C = HID / 8;   // 12 chunk-pairs per node
    int i = blockIdx.x * blockDim.x + threadIdx.x;
    if (i >= N_NODES * C) return;
    int n = i / C;
    int c = i - n * C;
    const float* t1a = T1 + c * 4;
    const float* t1b = T1 + (c + C) * 4;
    int k = row_off[n];
    int e = k + deg[n];
    float ax = 0.f, ay = 0.f, az = 0.f, aw = 0.f;
    float bx = 0.f, by = 0.f, bz = 0.f, bw = 0.f;
    for (; k + 3 < e; k += 4) {
        int2 i0 = node_info[csr[k]];
        int2 i1 = node_info[csr[k + 1]];
        int2 i2 = node_info[csr[k + 2]];
        int2 i3 = node_info[csr[k + 3]];
        int r0 = i0.x * HID, r1 = i1.x * HID, r2 = i2.x * HID, r3 = i3.x * HID;
        float4 aA = *(const float4*)(t1a + r0); float4 bA = *(const float4*)(t1b + r0);
        float4 aB = *(const float4*)(t1a + r1); float4 bB = *(const float4*)(t1b + r1);
        float4 aC = *(const float4*)(t1a + r2); float4 bC = *(const float4*)(t1b + r2);
        float4 aD = *(const float4*)(t1a + r3); float4 bD = *(const float4*)(t1b + r3);
        float w0 = __int_as_float(i0.y), w1 = __int_as_float(i1.y);
        float w2 = __int_as_float(i2.y), w3 = __int_as_float(i3.y);
        ax += aA.x * w0 + aB.x * w1 + aC.x * w2 + aD.x * w3;
        ay += aA.y * w0 + aB.y * w1 + aC.y * w2 + aD.y * w3;
        az += aA.z * w0 + aB.z * w1 + aC.z * w2 + aD.z * w3;
        aw += aA.w * w0 + aB.w * w1 + aC.w * w2 + aD.w * w3;
        bx += bA.x * w0 + bB.x * w1 + bC.x * w2 + bD.x * w3;
        by += bA.y * w0 + bB.y * w1 + bC.y * w2 + bD.y * w3;
        bz += bA.z * w0 + bB.z * w1 + bC.z * w2 + bD.z * w3;
        bw += bA.w * w0 + bB.w * w1 + bC.w * w2 + bD.w * w3;
    }
    for (; k < e; ++k) {
        int2 i0 = node_info[csr[k]];
        int r0 = i0.x * HID;
        float4 aA = *(const float4*)(t1a + r0); float4 bA = *(const float4*)(t1b + r0);
        float w0 = __int_as_float(i0.y);
        ax += aA.x * w0; ay += aA.y * w0; az += aA.z * w0; aw += aA.w * w0;
        bx += bA.x * w0; by += bA.y * w0; bz += bA.z * w0; bw += bA.w * w0;
    }
    float nn = in_norm[n];
    float on = out_norm[n];
    float4 b1a = *(const float4*)(b1 + c * 4);
    float4 b1b = *(const float4*)(b1 + (c + C) * 4);
    float4 rA, rB;
    rA.x = fmaxf(ax * nn + b1a.x, 0.f) * on; rA.y = fmaxf(ay * nn + b1a.y, 0.f) * on;
    rA.z = fmaxf(az * nn + b1a.z, 0.f) * on; rA.w = fmaxf(aw * nn + b1a.w, 0.f) * on;
    rB.x = fmaxf(bx * nn + b1b.x, 0.f) * on; rB.y = fmaxf(by * nn + b1b.y, 0.f) * on;
    rB.z = fmaxf(bz * nn + b1b.z, 0.f) * on; rB.w = fmaxf(bw * nn + b1b.w, 0.f) * on;
    float* op = h1s + (size_t)n * HID;
    *(float4*)(op + c * 4) = rA;
    *(float4*)(op + (c + C) * 4) = rB;
}

// Layer-2 aggregate: 2 float4 chunks per thread, unroll-4 edges.
// agg[n,:] = in_norm[n] * sum hs[csr[k],:]   (rows stride HID)
__global__ void gather4x2_kernel(const float* __restrict__ hs, const int* __restrict__ row_off,
                                 const int* __restrict__ deg, const int* __restrict__ csr,
                                 const float* __restrict__ in_norm, float* __restrict__ out) {
    constexpr int C = HID / 8;   // 12
    int i = blockIdx.x * blockDim.x + threadIdx.x;
    if (i >= N_NODES * C) return;
    int n = i / C;
    int c = i - n * C;
    const float* p0 = hs + c * 4;
    const float* p1 = hs + (c + C) * 4;
    int k = row_off[n];
    int e = k + deg[n];
    float ax = 0.f, ay = 0.f, az = 0.f, aw = 0.f;
    float bx = 0.f, by = 0.f, bz = 0.f, bw = 0.f;
    for (; k + 3 < e; k += 4) {
        size_t r0 = (size_t)csr[k] * HID,     r1 = (size_t)csr[k + 1] * HID;
        size_t r2 = (size_t)csr[k + 2] * HID, r3 = (size_t)csr[k + 3] * HID;
        float4 aA = *(const float4*)(p0 + r0); float4 bA = *(const float4*)(p1 + r0);
        float4 aB = *(const float4*)(p0 + r1); float4 bB = *(const float4*)(p1 + r1);
        float4 aC = *(const float4*)(p0 + r2); float4 bC = *(const float4*)(p1 + r2);
        float4 aD = *(const float4*)(p0 + r3); float4 bD = *(const float4*)(p1 + r3);
        ax += (aA.x + aB.x) + (aC.x + aD.x); ay += (aA.y + aB.y) + (aC.y + aD.y);
        az += (aA.z + aB.z) + (aC.z + aD.z); aw += (aA.w + aB.w) + (aC.w + aD.w);
        bx += (bA.x + bB.x) + (bC.x + bD.x); by += (bA.y + bB.y) + (bC.y + bD.y);
        bz += (bA.z + bB.z) + (bC.z + bD.z); bw += (bA.w + bB.w) + (bC.w + bD.w);
    }
    for (; k < e; ++k) {
        size_t r0 = (size_t)csr[k] * HID;
        float4 aA = *(const float4*)(p0 + r0); float4 bA = *(const float4*)(p1 + r0);
        ax += aA.x; ay += aA.y; az += aA.z; aw += aA.w;
        bx += bA.x; by += bA.y; bz += bA.z; bw += bA.w;
    }
    float nn = in_norm[n];
    float4 rA, rB;
    rA.x = ax * nn; rA.y = ay * nn; rA.z = az * nn; rA.w = aw * nn;
    rB.x = bx * nn; rB.y = by * nn; rB.z = bz * nn; rB.w = bw * nn;
    float* op = out + (size_t)n * HID;
    *(float4*)(op + c * 4) = rA;
    *(float4*)(op + (c + C) * 4) = rB;
}

// Fused layers 2+3: h2 = relu(agg@W2 + b2) * out_norm (kept in LDS),
// t = h2 @ W3 written with row stride TSTRIDE (cols 50,51 zero).
// h2s never touches global memory.
__global__ __launch_bounds__(256) void linear23_kernel(
        const float* __restrict__ agg, const float* __restrict__ W2,
        const float* __restrict__ b2, const float* __restrict__ out_norm,
        const float* __restrict__ W3, float* __restrict__ t) {
    constexpr int INP = 100;             // row stride: float4-aligned, banks offset 4/row
    __shared__ float in_s[64][INP];      // 25.6 KB
    __shared__ float W_s[HID * HID];     // 36.9 KB (phase 2 reuses as 96x64)
    __shared__ float bs[HID];
    const int tid = threadIdx.x;
    const int n0 = blockIdx.x * 64;

    // Stage agg tile (float4) + W2 (float4)
    for (int idx = tid; idx < 64 * (HID / 4); idx += 256) {
        int m = idx / (HID / 4), c = idx - m * (HID / 4);
        int n = n0 + m;
        float4 v = (n < N_NODES) ? *(const float4*)(agg + (size_t)n * HID + c * 4)
                                 : make_float4(0.f, 0.f, 0.f, 0.f);
        *(float4*)(&in_s[m][c * 4]) = v;
    }
    for (int idx = tid; idx < HID * HID / 4; idx += 256)
        *(float4*)(&W_s[idx * 4]) = *(const float4*)(W2 + idx * 4);
    if (tid < HID) bs[tid] = b2[tid];
    __syncthreads();

    const int tx = tid & 15, ty = tid >> 4;
    const int j0 = tx * 6, m0 = ty * 4;

    // GEMM1: 64x96 @ 96x96
    float acc[4][6];
#pragma unroll
    for (int i = 0; i < 4; ++i)
#pragma unroll
        for (int jj = 0; jj < 6; ++jj) acc[i][jj] = 0.0f;
#pragma unroll 4
    for (int k = 0; k < HID; ++k) {
        float a[4], w[6];
#pragma unroll
        for (int i = 0; i < 4; ++i) a[i] = in_s[m0 + i][k];
#pragma unroll
        for (int jj = 0; jj < 6; ++jj) w[jj] = W_s[k * HID + j0 + jj];
#pragma unroll
        for (int i = 0; i < 4; ++i)
#pragma unroll
            for (int jj = 0; jj < 6; ++jj) acc[i][jj] += a[i] * w[jj];
    }
    __syncthreads();   // all GEMM1 reads of in_s / W_s complete

    // h2 tile -> in_s (in place); W3 (zero-padded to 64 cols) -> W_s
#pragma unroll
    for (int i = 0; i < 4; ++i) {
        int n = n0 + m0 + i;
        float on = (n < N_NODES) ? out_norm[n] : 0.0f;
#pragma unroll
        for (int jj = 0; jj < 6; ++jj)
            in_s[m0 + i][j0 + jj] = fmaxf(acc[i][jj] + bs[j0 + jj], 0.0f) * on;
    }
    for (int idx = tid; idx < HID * 64; idx += 256) {
        int k = idx >> 6, j = idx & 63;
        W_s[idx] = (j < NLAB) ? W3[k * NLAB + j] : 0.0f;
    }
    __syncthreads();

    // GEMM2: 64x96 @ 96x64 (cols >= 50 are zero)
    const int j20 = tx * 4;
    float acc2[4][4];
#pragma unroll
    for (int i = 0; i < 4; ++i)
#pragma unroll
        for (int jj = 0; jj < 4; ++jj) acc2[i][jj] = 0.0f;
#pragma unroll 4
    for (int k = 0; k < HID; ++k) {
        float a[4], w[4];
#pragma unroll
        for (int i = 0; i < 4; ++i) a[i] = in_s[m0 + i][k];
#pragma unroll
        for (int jj = 0; jj < 4; ++jj) w[jj] = W_s[k * 64 + j20 + jj];
#pragma unroll
        for (int i = 0; i < 4; ++i)
#pragma unroll
            for (int jj = 0; jj < 4; ++jj) acc2[i][jj] += a[i] * w[jj];
    }
#pragma unroll
    for (int i = 0; i < 4; ++i) {
        int n = n0 + m0 + i;
        if (n >= N_NODES) break;
#pragma unroll
        for (int jj = 0; jj < 4; ++jj) {
            int j = j20 + jj;
            if (j < TSTRIDE) t[(size_t)n * TSTRIDE + j] = acc2[i][jj];
        }
    }
}

// Final gather over t (stride 52): out[n,:50] = in_norm[n]*sum t[src] + b3.
__global__ void gather_out_kernel(const float* __restrict__ t, const int* __restrict__ row_off,
                                  const int* __restrict__ deg, const int* __restrict__ csr,
                                  const float* __restrict__ in_norm, const float* __restrict__ bias,
                                  float* __restrict__ out) {
    constexpr int C = TSTRIDE / 4;  // 13
    int i = blockIdx.x * blockDim.x + threadIdx.x;
    if (i >= N_NODES * C) return;
    int n = i / C;
    int c = i - n * C;
    int k = row_off[n];
    int e = k + deg[n];
    float ax = 0.f, ay = 0.f, az = 0.f, aw = 0.f;
    for (; k + 3 < e; k += 4) {
        int s0 = csr[k], s1 = csr[k + 1], s2 = csr[k + 2], s3 = csr[k + 3];
        float4 v0 = *(const float4*)(t + (size_t)s0 * TSTRIDE + c * 4);
        float4 v1 = *(const float4*)(t + (size_t)s1 * TSTRIDE + c * 4);
        float4 v2 = *(const float4*)(t + (size_t)s2 * TSTRIDE + c * 4);
        float4 v3 = *(const float4*)(t + (size_t)s3 * TSTRIDE + c * 4);
        ax += (v0.x + v1.x) + (v2.x + v3.x);
        ay += (v0.y + v1.y) + (v2.y + v3.y);
        az += (v0.z + v1.z) + (v2.z + v3.z);
        aw += (v0.w + v1.w) + (v2.w + v3.w);
    }
    for (; k < e; ++k) {
        float4 v0 = *(const float4*)(t + (size_t)csr[k] * TSTRIDE + c * 4);
        ax += v0.x; ay += v0.y; az += v0.z; aw += v0.w;
    }
    float nn = in_norm[n];
    int j = c * 4;
    float* op = out + (size_t)n * NLAB + j;   // rows 8B-aligned only -> float2 stores
    float2 lo; lo.x = ax * nn + bias[j];     lo.y = ay * nn + bias[j + 1];
    *(float2*)op = lo;
    if (j + 2 < NLAB) {
        float2 hi; hi.x = az * nn + bias[j + 2]; hi.y = aw * nn + bias[j + 3];
        *(float2*)(op + 2) = hi;
    }
}

static inline int cdiv(long a, int b) { return (int)((a + b - 1) / b); }

extern "C" void kernel_launch(void* const* d_in, const int* in_sizes, int n_in,
                              void* d_out, int out_size, void* d_ws, size_t ws_size,
                              hipStream_t stream) {
    const int*   dep_labels = (const int*)d_in[0];
    const int*   src        = (const int*)d_in[1];
    const int*   dst        = (const int*)d_in[2];
    const float* emb        = (const float*)d_in[3];
    const float* W1 = (const float*)d_in[4]; const float* b1 = (const float*)d_in[5];
    const float* W2 = (const float*)d_in[6]; const float* b2 = (const float*)d_in[7];
    const float* W3 = (const float*)d_in[8]; const float* b3 = (const float*)d_in[9];
    float* out = (float*)d_out;

    // ---- workspace layout ----
    int* wsp        = (int*)d_ws;
    int* deg_out_i  = wsp;                 wsp += N_NODES;
    int* deg_in_i   = wsp;                 wsp += N_NODES;
    int* row_off    = wsp;                 wsp += N_NODES;
    int* rank       = wsp;                 wsp += N_EDGES;
    int* bsum       = wsp;                 wsp += 256;
    int* bscan      = wsp;                 wsp += 256;
    int* csr_src    = wsp;                 wsp += N_EDGES;
    float* out_norm = (float*)wsp;         wsp += N_NODES;
    float* in_norm  = (float*)wsp;         wsp += N_NODES;
    int2* node_info = (int2*)wsp;          wsp += 2 * N_NODES;
    float* T1       = (float*)wsp;         wsp += NLAB * HID;
    float* bufA     = (float*)wsp;         wsp += (size_t)N_NODES * HID;   // agg
    float* bufB     = (float*)wsp;         // h1s, then t (N_NODES*HID)

    const int B = 256;
    const int NLIN = cdiv(N_NODES, 64);    // 782

    hipMemsetAsync(deg_out_i, 0, 2 * N_NODES * sizeof(int), stream);
    deg_rank_kernel<<<cdiv(N_EDGES, B), B, 0, stream>>>(src, dst, deg_out_i, deg_in_i, rank);
    t1_kernel<<<cdiv(NLAB * HID, B), B, 0, stream>>>(emb, W1, T1);

    scan1_kernel<<<NB_SCAN, 256, 0, stream>>>(deg_in_i, bsum);
    scan2_kernel<<<1, 256, 0, stream>>>(bsum, bscan);
    scan3_kernel<<<NB_SCAN, 256, 0, stream>>>(deg_in_i, bscan, deg_out_i, dep_labels,
                                              row_off, out_norm, in_norm, node_info);
    fill_kernel<<<cdiv(N_EDGES, B), B, 0, stream>>>(src, dst, row_off, rank, csr_src);

    // Layer 1 fused: gather over T1 with relu/bias/norm epilogue -> h1s
    gather1t_kernel<<<cdiv((long)N_NODES * (HID / 8), B), B, 0, stream>>>(
        node_info, T1, row_off, deg_in_i, csr_src, in_norm, out_norm, b1, bufB);

    // Layer 2 aggregate -> agg
    gather4x2_kernel<<<cdiv((long)N_NODES * (HID / 8), B), B, 0, stream>>>(
        bufB, row_off, deg_in_i, csr_src, in_norm, bufA);

    // Layers 2+3 fused transform: agg -> t (h2 stays in LDS)
    linear23_kernel<<<NLIN, 256, 0, stream>>>(bufA, W2, b2, out_norm, W3, bufB);

    // Final gather + bias
    gather_out_kernel<<<cdiv((long)N_NODES * (TSTRIDE / 4), B), B, 0, stream>>>(
        bufB, row_off, deg_in_i, csr_src, in_norm, b3, out);
}